// Round 12
// baseline (126.481 us; speedup 1.0000x reference)
//
#include <hip/hip_runtime.h>

typedef short bf8 __attribute__((ext_vector_type(8)));   // 8 bf16 in 4 VGPRs
typedef float f32x4 __attribute__((ext_vector_type(4)));
typedef float f32x16 __attribute__((ext_vector_type(16)));
typedef int i32x4 __attribute__((ext_vector_type(4)));

__device__ __forceinline__ ushort f2b(float f) {
  unsigned x = __builtin_bit_cast(unsigned, f);
  unsigned r = (x + 0x7fffu + ((x >> 16) & 1u)) >> 16;
  return (ushort)r;
}
__device__ __forceinline__ float b2f(ushort u) {
  unsigned x = ((unsigned)u) << 16;
  return __builtin_bit_cast(float, x);
}

__device__ __forceinline__ f32x4 mfma16(bf8 a, bf8 b, f32x4 c) {
  return __builtin_amdgcn_mfma_f32_16x16x32_bf16(a, b, c, 0, 0, 0);
}
__device__ __forceinline__ f32x16 mfma32(bf8 a, bf8 b, f32x16 c) {
  return __builtin_amdgcn_mfma_f32_32x32x16_bf16(a, b, c, 0, 0, 0);
}

__device__ __forceinline__ float fexp2(float x) {
#if __has_builtin(__builtin_amdgcn_exp2f)
  return __builtin_amdgcn_exp2f(x);
#else
  return exp2f(x);
#endif
}

__device__ __forceinline__ uint cvtpk(float lo, float hi_) {
  uint r;
  asm("v_cvt_pk_bf16_f32 %0, %1, %2" : "=v"(r) : "v"(lo), "v"(hi_));
  return r;
}
__device__ __forceinline__ void plswap(uint& a, uint& b) {
  asm("v_permlane32_swap_b32 %0, %1" : "+v"(a), "+v"(b));
}

__device__ __forceinline__ void gload16(const ushort* g, ushort* l) {
  __builtin_amdgcn_global_load_lds(
      (const __attribute__((address_space(1))) void*)g,
      (__attribute__((address_space(3))) void*)l, 16, 0, 0);
}

// ---------------- prep1: cast x (f32->bf16) + all weight transposes ------
__global__ __launch_bounds__(256) void prep1(
    const float* __restrict__ x, const float* __restrict__ wq,
    const float* __restrict__ wk, const float* __restrict__ wv,
    const float* __restrict__ wo, ushort* __restrict__ xb,
    ushort* __restrict__ wqkvT, ushort* __restrict__ woT) {
  __shared__ float tile[32][33];
  const int bid = blockIdx.x;
  if (bid < 4096) {
    const int i = (bid * 256 + threadIdx.x) * 4;
    float4 v = *(const float4*)(x + i);
    ushort4 o;
    o.x = f2b(v.x); o.y = f2b(v.y); o.z = f2b(v.z); o.w = f2b(v.w);
    *(ushort4*)(xb + i) = o;
    return;
  }
  int t = bid - 4096;  // 0..2559
  const float* src;
  ushort* dst;
  int N;
  if (t < 1024) {
    src = wq; dst = wqkvT; N = 1024;
  } else if (t < 1280) {
    src = wk; dst = wqkvT + 1024 * 1024; N = 256; t -= 1024;
  } else if (t < 1536) {
    src = wv; dst = wqkvT + 1280 * 1024; N = 256; t -= 1280;
  } else {
    src = wo; dst = woT; N = 1024; t -= 1536;
  }
  const int kx = (t & 31) * 32, nx = (t >> 5) * 32;
  const int tx = threadIdx.x & 31, ty = threadIdx.x >> 5;
#pragma unroll
  for (int i = ty; i < 32; i += 8)
    tile[i][tx] = src[(size_t)(kx + i) * N + nx + tx];
  __syncthreads();
#pragma unroll
  for (int i = ty; i < 32; i += 8)
    dst[(size_t)(nx + i) * 1024 + kx + tx] = f2b(tile[tx][i]);
}

// ---------------- GEMM C[M][N] = A[M][K] * Bt[N][K]^T ----------------
template <bool OUT_BF16>
__global__ __launch_bounds__(256) void gemm_bt(const ushort* __restrict__ A,
                                               const ushort* __restrict__ Bt,
                                               void* __restrict__ Cv, int M,
                                               int N, int K) {
  __shared__ ushort aL[128 * 32];
  __shared__ ushort bL[128 * 32];
  const int tid = threadIdx.x;
  const int wid = tid >> 6, lane = tid & 63;
  const int l15 = lane & 15, l4 = lane >> 4;
  const int bm = blockIdx.y * 128, bn = blockIdx.x * 128;
  const int wr = (wid >> 1) * 64, wc = (wid & 1) * 64;
  f32x4 acc[4][4] = {};
  for (int kb = 0; kb < K; kb += 32) {
    __syncthreads();
#pragma unroll
    for (int i = 0; i < 2; ++i) {
      const int e = (i * 256 + tid) * 8;
      const int r = e >> 5, c = e & 31;
      gload16(A + (size_t)(bm + r) * K + kb + c, &aL[i * 2048 + wid * 512]);
      gload16(Bt + (size_t)(bn + r) * K + kb + c, &bL[i * 2048 + wid * 512]);
    }
    asm volatile("s_waitcnt vmcnt(0)" ::: "memory");
    __syncthreads();
    bf8 af[4], bfr[4];
#pragma unroll
    for (int i = 0; i < 4; ++i) {
      af[i] = *(const bf8*)&aL[(wr + i * 16 + l15) * 32 + l4 * 8];
      bfr[i] = *(const bf8*)&bL[(wc + i * 16 + l15) * 32 + l4 * 8];
    }
#pragma unroll
    for (int i = 0; i < 4; ++i)
#pragma unroll
      for (int j = 0; j < 4; ++j)
        acc[i][j] = mfma16(af[i], bfr[j], acc[i][j]);
  }
#pragma unroll
  for (int i = 0; i < 4; ++i)
#pragma unroll
    for (int j = 0; j < 4; ++j)
#pragma unroll
      for (int r = 0; r < 4; ++r) {
        const size_t row = bm + wr + i * 16 + l4 * 4 + r;
        const size_t col = bn + wc + j * 16 + l15;
        if constexpr (OUT_BF16)
          ((ushort*)Cv)[row * N + col] = f2b(acc[i][j][r]);
        else
          ((float*)Cv)[row * N + col] = acc[i][j][r];
      }
}

// ---------------- prep2: RoPE for Q,K + V transpose ----------------
// Q is pre-scaled by 0.125*log2(e) so attention scores are in log2 domain.
__global__ __launch_bounds__(256) void prep2(const ushort* __restrict__ qkv,
                                             const float* __restrict__ fc,
                                             const float* __restrict__ fs,
                                             ushort* __restrict__ qh,
                                             ushort* __restrict__ kh,
                                             ushort* __restrict__ vT) {
  __shared__ ushort tile[64][65];
  if (blockIdx.x < 10240) {
    const int idx = blockIdx.x * 256 + threadIdx.x;  // 4096*640 total
    const int u = idx % 640;
    const int m = idx / 640;
    const int s = m & 2047, b = m >> 11;
    int col, j;
    if (u < 512) {
      j = u & 31;
      col = (u >> 5) * 64 + 2 * j;
    } else {
      j = (u - 512) & 31;
      col = 1024 + ((u - 512) >> 5) * 64 + 2 * j;
    }
    const uint pr = *(const uint*)(qkv + (size_t)m * 1536 + col);
    const float tr = b2f((ushort)(pr & 0xffff));
    const float ti = b2f((ushort)(pr >> 16));
    const float c = fc[s * 32 + j], sn = fs[s * 32 + j];
    float orr = tr * c - ti * sn;
    float oi = tr * sn + ti * c;
    if (u < 512) {
      orr *= 0.18033688f;  // (1/sqrt(64)) * log2(e)
      oi *= 0.18033688f;
      const uint w = (uint)f2b(orr) | ((uint)f2b(oi) << 16);
      *(uint*)(qh + ((size_t)(b * 16 + (u >> 5)) * 2048 + s) * 64 + 2 * j) = w;
    } else {
      const uint w = (uint)f2b(orr) | ((uint)f2b(oi) << 16);
      const int kv = (u - 512) >> 5;
      *(uint*)(kh + ((size_t)(b * 4 + kv) * 2048 + s) * 64 + 2 * j) = w;
    }
    return;
  }
  // V transpose: 256 blocks
  const int id = blockIdx.x - 10240;
  const int st = id & 31, kv = (id >> 5) & 3, b = id >> 7;
  const int tid = threadIdx.x;
  for (int e = tid; e < 4096; e += 256) {
    const int r = e >> 6, c = e & 63;
    tile[r][c] =
        qkv[(size_t)(b * 2048 + st * 64 + r) * 1536 + 1280 + kv * 64 + c];
  }
  __syncthreads();
  for (int e = tid; e < 4096; e += 256) {
    const int d = e >> 6, c = e & 63;
    vT[((size_t)(b * 4 + kv) * 64 + d) * 2048 + st * 64 + c] = tile[c][d];
  }
}

// ---------------- Flash attention v8: uniform 11-step 3-chunk blocks ------
// 3072 blocks x 64 thr. Pair p: tiles tA=p (nA=(p+2)>>1 slots) + tB=63-p
// (nB=33-nA); 33 slots split into chunks [11c, 11c+11), c=0..2. Every block
// runs exactly 11 steps; the one chunk spanning the A/B boundary prefetches
// B's first KV tile during A's last step. Fixed-max softmax => partials are
// additive; A has <=2 contributors (c0; c1 iff nA>11), B <=3 (c1,c2; c0 iff
// nA<11). combine() knows the contributor set statically from p.

#define MCONST 12.0f

__device__ __forceinline__ void astep2(const bf8 (&kfA)[4], const bf8 (&kfB)[4],
                                       const bf8 (&vfA)[4], const bf8 (&vfB)[4],
                                       const bf8 (&qf)[4], f32x16& o0,
                                       f32x16& o1, float& l, int k0, int qg,
                                       bool maskt, int hi) {
  f32x16 s0 = {}, s1 = {};
  __builtin_amdgcn_s_setprio(1);
#pragma unroll
  for (int ks = 0; ks < 4; ++ks) s0 = mfma32(kfA[ks], qf[ks], s0);
#pragma unroll
  for (int ks = 0; ks < 4; ++ks) s1 = mfma32(kfB[ks], qf[ks], s1);
  __builtin_amdgcn_s_setprio(0);
  if (maskt) {
#pragma unroll
    for (int r = 0; r < 16; ++r) {
      const int key = k0 + (r & 3) + 8 * (r >> 2) + 4 * hi;
      if (key > qg) s0[r] = -1e30f;
      if (key + 32 > qg) s1[r] = -1e30f;
    }
  }
  float t[16];
#pragma unroll
  for (int r = 0; r < 16; ++r) {
    s0[r] = fexp2(s0[r] - MCONST);
    s1[r] = fexp2(s1[r] - MCONST);
    t[r] = s0[r] + s1[r];
  }
#pragma unroll
  for (int st = 8; st > 0; st >>= 1)
#pragma unroll
    for (int r = 0; r < st; ++r) t[r] += t[r + st];
  l += t[0] + __shfl_xor(t[0], 32);
  bf8 pa[4];
  {
    uint a0 = cvtpk(s0[0], s0[1]), a1 = cvtpk(s0[2], s0[3]);
    uint b0 = cvtpk(s0[4], s0[5]), b1 = cvtpk(s0[6], s0[7]);
    plswap(a0, b0);
    plswap(a1, b1);
    i32x4 w = {(int)a0, (int)a1, (int)b0, (int)b1};
    pa[0] = __builtin_bit_cast(bf8, w);
    uint c0 = cvtpk(s0[8], s0[9]), c1 = cvtpk(s0[10], s0[11]);
    uint d0 = cvtpk(s0[12], s0[13]), d1 = cvtpk(s0[14], s0[15]);
    plswap(c0, d0);
    plswap(c1, d1);
    i32x4 w2 = {(int)c0, (int)c1, (int)d0, (int)d1};
    pa[1] = __builtin_bit_cast(bf8, w2);
  }
  {
    uint a0 = cvtpk(s1[0], s1[1]), a1 = cvtpk(s1[2], s1[3]);
    uint b0 = cvtpk(s1[4], s1[5]), b1 = cvtpk(s1[6], s1[7]);
    plswap(a0, b0);
    plswap(a1, b1);
    i32x4 w = {(int)a0, (int)a1, (int)b0, (int)b1};
    pa[2] = __builtin_bit_cast(bf8, w);
    uint c0 = cvtpk(s1[8], s1[9]), c1 = cvtpk(s1[10], s1[11]);
    uint d0 = cvtpk(s1[12], s1[13]), d1 = cvtpk(s1[14], s1[15]);
    plswap(c0, d0);
    plswap(c1, d1);
    i32x4 w2 = {(int)c0, (int)c1, (int)d0, (int)d1};
    pa[3] = __builtin_bit_cast(bf8, w2);
  }
  __builtin_amdgcn_s_setprio(1);
#pragma unroll
  for (int ks = 0; ks < 4; ++ks) o0 = mfma32(vfA[ks], pa[ks], o0);
#pragma unroll
  for (int ks = 0; ks < 4; ++ks) o1 = mfma32(vfB[ks], pa[ks], o1);
  __builtin_amdgcn_s_setprio(0);
}

// write raw (O,l) partial: O bf16 [32 rows][64 d], l f32 [32]
__device__ __forceinline__ void part_out(ushort* dst, float* lw,
                                         const f32x16& o0, const f32x16& o1,
                                         float l, int l31, int hi) {
#pragma unroll
  for (int dt = 0; dt < 2; ++dt)
#pragma unroll
    for (int rq = 0; rq < 4; ++rq) {
      const f32x16& ac = dt ? o1 : o0;
      uint2 w;
      w.x = (uint)f2b(ac[rq * 4 + 0]) | ((uint)f2b(ac[rq * 4 + 1]) << 16);
      w.y = (uint)f2b(ac[rq * 4 + 2]) | ((uint)f2b(ac[rq * 4 + 3]) << 16);
      const int d = dt * 32 + 8 * rq + 4 * hi;
      *(uint2*)&dst[l31 * 64 + d] = w;
    }
  if (hi == 0) lw[l31] = l;
}

__global__ __launch_bounds__(64) void attn_fwd(const ushort* __restrict__ qh,
                                               const ushort* __restrict__ kh,
                                               const ushort* __restrict__ vT,
                                               ushort* __restrict__ wsA,
                                               ushort* __restrict__ wsB,
                                               float* __restrict__ wslA,
                                               float* __restrict__ wslB) {
  __shared__ ushort kls[4096];  // 8KB K tile (64x64 bf16, swizzled)
  __shared__ ushort vls[4096];  // 8KB V tile (64d x 64k, swizzled)
  const int lane = threadIdx.x;
  const int l31 = lane & 31, hi = lane >> 5;
  const int gid = blockIdx.x;  // 3072
  const int bh = gid & 31;
  const int r = gid >> 5;      // 0..95
  const int p = r & 31;        // pair id
  const int c = r >> 5;        // chunk 0..2
  const int b = bh >> 4, h = bh & 15;
  const int kv = h >> 2;
  const int tA = p, tB = 63 - p;
  const int nA = (p + 2) >> 1;  // 1..16
  const int nB = 33 - nA;
  const int pb = (bh << 5) | p;

  const int aLo = min(c * 11, nA), aHi = min(c * 11 + 11, nA);
  const int bLo = max(c * 11, nA) - nA;
  int bHi = c * 11 + 11 - nA;
  if (bHi < bLo) bHi = bLo;
  const bool hasA = aHi > aLo, hasB = bHi > bLo;

  const ushort* kbase = kh + (size_t)(b * 4 + kv) * 2048 * 64;
  const ushort* vbase = vT + (size_t)(b * 4 + kv) * 64 * 2048;
  const int sw0 = l31 & 7;

  auto stage = [&](int k0) {
#pragma unroll
    for (int jj = 0; jj < 8; ++jj) {
      const int i = jj * 64 + lane;
      const int rr = i >> 3, s = i & 7;
      const int sw = (s ^ (rr & 7)) << 3;
      gload16(kbase + (size_t)(k0 + rr) * 64 + sw, kls + jj * 512);
      gload16(vbase + (size_t)rr * 2048 + k0 + sw, vls + jj * 512);
    }
  };
  auto loadQ = [&](int t, bf8(&qf)[4]) {
    const ushort* qb = qh + ((size_t)bh * 2048 + t * 32 + l31) * 64 + hi * 8;
#pragma unroll
    for (int ks = 0; ks < 4; ++ks) qf[ks] = *(const bf8*)(qb + ks * 16);
  };
  auto readfrags = [&](bf8(&kfA)[4], bf8(&kfB)[4], bf8(&vfA)[4],
                       bf8(&vfB)[4]) {
    asm volatile("s_waitcnt vmcnt(0)" ::: "memory");
#pragma unroll
    for (int ks = 0; ks < 4; ++ks) {
      const int c2 = 2 * ks + hi;
      const int off = (c2 ^ sw0) << 3;
      kfA[ks] = *(const bf8*)&kls[l31 * 64 + off];
      kfB[ks] = *(const bf8*)&kls[(32 + l31) * 64 + off];
      vfA[ks] = *(const bf8*)&vls[l31 * 64 + off];
      vfB[ks] = *(const bf8*)&vls[(32 + l31) * 64 + off];
    }
    asm volatile("s_waitcnt lgkmcnt(0)" ::: "memory");
    __builtin_amdgcn_sched_barrier(0);
  };

  bf8 qf[4];
  f32x16 o0 = {}, o1 = {};
  float l = 0.f;

  stage((hasA ? aLo : bLo) * 64);

  if (hasA) {
    loadQ(tA, qf);
    const int qgA = tA * 32 + l31;
    for (int j = aLo; j < aHi; ++j) {
      bf8 kfA[4], kfB[4], vfA[4], vfB[4];
      readfrags(kfA, kfB, vfA, vfB);
      if (j + 1 < aHi)
        stage((j + 1) * 64);
      else if (hasB)
        stage(bLo * 64);  // prefetch B's first tile during last A step
      astep2(kfA, kfB, vfA, vfB, qf, o0, o1, l, j * 64, qgA, j == nA - 1, hi);
    }
    const int slot = pb * 2 + (c ? 1 : 0);
    part_out(wsA + (size_t)slot * 2048, wslA + slot * 32, o0, o1, l, l31, hi);
#pragma unroll
    for (int e = 0; e < 16; ++e) {
      o0[e] = 0.f;
      o1[e] = 0.f;
    }
    l = 0.f;
  }
  if (hasB) {
    loadQ(tB, qf);
    const int qgB = tB * 32 + l31;
    for (int j = bLo; j < bHi; ++j) {
      bf8 kfA[4], kfB[4], vfA[4], vfB[4];
      readfrags(kfA, kfB, vfA, vfB);
      if (j + 1 < bHi) stage((j + 1) * 64);
      astep2(kfA, kfB, vfA, vfB, qf, o0, o1, l, j * 64, qgB, j == nB - 1, hi);
    }
    const int slot = pb * 3 + c;
    part_out(wsB + (size_t)slot * 2048, wslB + slot * 32, o0, o1, l, l31, hi);
  }
}

// ---------------- combine: sum partials, normalize, write ao --------------
__global__ __launch_bounds__(256) void combine(const ushort* __restrict__ wsA,
                                               const ushort* __restrict__ wsB,
                                               const float* __restrict__ wslA,
                                               const float* __restrict__ wslB,
                                               ushort* __restrict__ ao) {
  const int bid = blockIdx.x;  // 2048
  const int pb = bid >> 1, which = bid & 1;
  const int bh = pb >> 5, p = pb & 31;
  const int b = bh >> 4, h = bh & 15;
  const int nA = (p + 2) >> 1;
  const int tid = threadIdx.x;
  const int row = tid >> 3, dg = (tid & 7) * 8;
  float a8[8] = {};
  float lsum = 0.f;
  auto addslot = [&](const ushort* O, const float* L) {
    const uint4 v = *(const uint4*)(O + row * 64 + dg);
    const uint vv[4] = {v.x, v.y, v.z, v.w};
#pragma unroll
    for (int i = 0; i < 4; ++i) {
      a8[2 * i] += b2f((ushort)(vv[i] & 0xffff));
      a8[2 * i + 1] += b2f((ushort)(vv[i] >> 16));
    }
    lsum += L[row];
  };
  int t;
  if (which == 0) {  // tile tA = p
    addslot(wsA + (size_t)(pb * 2) * 2048, wslA + (pb * 2) * 32);
    if (nA > 11) addslot(wsA + (size_t)(pb * 2 + 1) * 2048, wslA + (pb * 2 + 1) * 32);
    t = p;
  } else {  // tile tB = 63 - p
    if (nA < 11) addslot(wsB + (size_t)(pb * 3) * 2048, wslB + (pb * 3) * 32);
    addslot(wsB + (size_t)(pb * 3 + 1) * 2048, wslB + (pb * 3 + 1) * 32);
    addslot(wsB + (size_t)(pb * 3 + 2) * 2048, wslB + (pb * 3 + 2) * 32);
    t = 63 - p;
  }
  const float inv = 1.0f / lsum;
  uint4 o;
  uint res[4];
#pragma unroll
  for (int i = 0; i < 4; ++i)
    res[i] = (uint)f2b(a8[2 * i] * inv) | ((uint)f2b(a8[2 * i + 1] * inv) << 16);
  o.x = res[0]; o.y = res[1]; o.z = res[2]; o.w = res[3];
  *(uint4*)&ao[((size_t)b * 2048 + t * 32 + row) * 1024 + h * 64 + dg] = o;
}

extern "C" void kernel_launch(void* const* d_in, const int* in_sizes, int n_in,
                              void* d_out, int out_size, void* d_ws,
                              size_t ws_size, hipStream_t stream) {
  (void)in_sizes; (void)n_in; (void)out_size; (void)ws_size;
  const float* x = (const float*)d_in[0];
  const float* wq = (const float*)d_in[1];
  const float* wk = (const float*)d_in[2];
  const float* wv = (const float*)d_in[3];
  const float* wo = (const float*)d_in[4];
  const float* fc = (const float*)d_in[5];
  const float* fs = (const float*)d_in[6];
  float* out = (float*)d_out;

  ushort* xb = (ushort*)d_ws;               // 4096x1024; reused as wsA (2x1024x2048)
  ushort* wqkvT = xb + 4194304;             // 1536x1024; reused as wslA/wslB (f32)
  ushort* woT = wqkvT + 1572864;            // 1024x1024
  ushort* qkv = woT + 1048576;              // 4096x1536; reused as wsB (3x1024x2048)
  ushort* qh = qkv + 6291456;               // 32x2048x64
  ushort* kh = qh + 4194304;                // 8x2048x64
  ushort* vTb = kh + 1048576;               // 8x64x2048
  ushort* ao = vTb + 1048576;               // 4096x1024
  float* wslA = (float*)wqkvT;              // 2x1024x32 f32 (wqkvT dead post-gemm1)
  float* wslB = wslA + 65536;               // 3x1024x32 f32

  prep1<<<6656, 256, 0, stream>>>(x, wq, wk, wv, wo, xb, wqkvT, woT);
  gemm_bt<true><<<dim3(12, 32), 256, 0, stream>>>(xb, wqkvT, qkv, 4096, 1536, 1024);
  prep2<<<10496, 256, 0, stream>>>(qkv, fc, fs, qh, kh, vTb);
  attn_fwd<<<3072, 64, 0, stream>>>(qh, kh, vTb, xb, qkv, wslA, wslB);
  combine<<<2048, 256, 0, stream>>>(xb, qkv, wslA, wslB, ao);
  gemm_bt<false><<<dim3(8, 32), 256, 0, stream>>>(ao, woT, out, 4096, 1024, 1024);
}

// Round 13
// 116.902 us; speedup vs baseline: 1.0819x; 1.0819x over previous
//
#include <hip/hip_runtime.h>

typedef short bf8 __attribute__((ext_vector_type(8)));   // 8 bf16 in 4 VGPRs
typedef float f32x4 __attribute__((ext_vector_type(4)));
typedef float f32x16 __attribute__((ext_vector_type(16)));
typedef int i32x4 __attribute__((ext_vector_type(4)));

__device__ __forceinline__ ushort f2b(float f) {
  unsigned x = __builtin_bit_cast(unsigned, f);
  unsigned r = (x + 0x7fffu + ((x >> 16) & 1u)) >> 16;
  return (ushort)r;
}
__device__ __forceinline__ float b2f(ushort u) {
  unsigned x = ((unsigned)u) << 16;
  return __builtin_bit_cast(float, x);
}

__device__ __forceinline__ f32x4 mfma16(bf8 a, bf8 b, f32x4 c) {
  return __builtin_amdgcn_mfma_f32_16x16x32_bf16(a, b, c, 0, 0, 0);
}
__device__ __forceinline__ f32x16 mfma32(bf8 a, bf8 b, f32x16 c) {
  return __builtin_amdgcn_mfma_f32_32x32x16_bf16(a, b, c, 0, 0, 0);
}

__device__ __forceinline__ float fexp2(float x) {
#if __has_builtin(__builtin_amdgcn_exp2f)
  return __builtin_amdgcn_exp2f(x);
#else
  return exp2f(x);
#endif
}

__device__ __forceinline__ uint cvtpk(float lo, float hi_) {
  uint r;
  asm("v_cvt_pk_bf16_f32 %0, %1, %2" : "=v"(r) : "v"(lo), "v"(hi_));
  return r;
}
__device__ __forceinline__ void plswap(uint& a, uint& b) {
  asm("v_permlane32_swap_b32 %0, %1" : "+v"(a), "+v"(b));
}

__device__ __forceinline__ void gload16(const ushort* g, ushort* l) {
  __builtin_amdgcn_global_load_lds(
      (const __attribute__((address_space(1))) void*)g,
      (__attribute__((address_space(3))) void*)l, 16, 0, 0);
}

// ---------------- prep1: cast x (f32->bf16) + all weight transposes ------
__global__ __launch_bounds__(256) void prep1(
    const float* __restrict__ x, const float* __restrict__ wq,
    const float* __restrict__ wk, const float* __restrict__ wv,
    const float* __restrict__ wo, ushort* __restrict__ xb,
    ushort* __restrict__ wqkvT, ushort* __restrict__ woT) {
  __shared__ float tile[32][33];
  const int bid = blockIdx.x;
  if (bid < 4096) {
    const int i = (bid * 256 + threadIdx.x) * 4;
    float4 v = *(const float4*)(x + i);
    ushort4 o;
    o.x = f2b(v.x); o.y = f2b(v.y); o.z = f2b(v.z); o.w = f2b(v.w);
    *(ushort4*)(xb + i) = o;
    return;
  }
  int t = bid - 4096;  // 0..2559
  const float* src;
  ushort* dst;
  int N;
  if (t < 1024) {
    src = wq; dst = wqkvT; N = 1024;
  } else if (t < 1280) {
    src = wk; dst = wqkvT + 1024 * 1024; N = 256; t -= 1024;
  } else if (t < 1536) {
    src = wv; dst = wqkvT + 1280 * 1024; N = 256; t -= 1280;
  } else {
    src = wo; dst = woT; N = 1024; t -= 1536;
  }
  const int kx = (t & 31) * 32, nx = (t >> 5) * 32;
  const int tx = threadIdx.x & 31, ty = threadIdx.x >> 5;
#pragma unroll
  for (int i = ty; i < 32; i += 8)
    tile[i][tx] = src[(size_t)(kx + i) * N + nx + tx];
  __syncthreads();
#pragma unroll
  for (int i = ty; i < 32; i += 8)
    dst[(size_t)(nx + i) * 1024 + kx + tx] = f2b(tile[tx][i]);
}

// ------- GEMM C[M][N] = A[M][K]*Bt[N][K]^T; 64x128 tile, 4 waves ---------
// 768/512 blocks -> exactly 3/2 blocks per CU (integer balance, 12/8 waves).
template <bool OUT_BF16>
__global__ __launch_bounds__(256) void gemm_bt(const ushort* __restrict__ A,
                                               const ushort* __restrict__ Bt,
                                               void* __restrict__ Cv, int M,
                                               int N, int K) {
  __shared__ ushort aL[64 * 32];    // 4 KB
  __shared__ ushort bL[128 * 32];   // 8 KB
  const int tid = threadIdx.x;
  const int wid = tid >> 6, lane = tid & 63;
  const int l15 = lane & 15, l4 = lane >> 4;
  const int bm = blockIdx.y * 64, bn = blockIdx.x * 128;
  const int wr = (wid & 1) * 32, wc = (wid >> 1) * 64;
  f32x4 acc[2][4] = {};
  for (int kb = 0; kb < K; kb += 32) {
    __syncthreads();
    {
      const int e = tid * 8;  // A: 256 chunks, 1/thread
      const int r = e >> 5, c = e & 31;
      gload16(A + (size_t)(bm + r) * K + kb + c, &aL[wid * 512]);
    }
#pragma unroll
    for (int i = 0; i < 2; ++i) {  // B: 512 chunks, 2/thread
      const int e = (i * 256 + tid) * 8;
      const int r = e >> 5, c = e & 31;
      gload16(Bt + (size_t)(bn + r) * K + kb + c, &bL[i * 2048 + wid * 512]);
    }
    asm volatile("s_waitcnt vmcnt(0)" ::: "memory");
    __syncthreads();
    bf8 af[2], bfr[4];
#pragma unroll
    for (int i = 0; i < 2; ++i)
      af[i] = *(const bf8*)&aL[(wr + i * 16 + l15) * 32 + l4 * 8];
#pragma unroll
    for (int j = 0; j < 4; ++j)
      bfr[j] = *(const bf8*)&bL[(wc + j * 16 + l15) * 32 + l4 * 8];
#pragma unroll
    for (int i = 0; i < 2; ++i)
#pragma unroll
      for (int j = 0; j < 4; ++j)
        acc[i][j] = mfma16(af[i], bfr[j], acc[i][j]);
  }
#pragma unroll
  for (int i = 0; i < 2; ++i)
#pragma unroll
    for (int j = 0; j < 4; ++j)
#pragma unroll
      for (int r = 0; r < 4; ++r) {
        const size_t row = bm + wr + i * 16 + l4 * 4 + r;
        const size_t col = bn + wc + j * 16 + l15;
        if constexpr (OUT_BF16)
          ((ushort*)Cv)[row * N + col] = f2b(acc[i][j][r]);
        else
          ((float*)Cv)[row * N + col] = acc[i][j][r];
      }
}

// ---------------- prep2: RoPE for Q,K + V transpose ----------------
// Q is pre-scaled by 0.125*log2(e) so attention scores are in log2 domain.
__global__ __launch_bounds__(256) void prep2(const ushort* __restrict__ qkv,
                                             const float* __restrict__ fc,
                                             const float* __restrict__ fs,
                                             ushort* __restrict__ qh,
                                             ushort* __restrict__ kh,
                                             ushort* __restrict__ vT) {
  __shared__ ushort tile[64][65];
  if (blockIdx.x < 10240) {
    const int idx = blockIdx.x * 256 + threadIdx.x;  // 4096*640 total
    const int u = idx % 640;
    const int m = idx / 640;
    const int s = m & 2047, b = m >> 11;
    int col, j;
    if (u < 512) {
      j = u & 31;
      col = (u >> 5) * 64 + 2 * j;
    } else {
      j = (u - 512) & 31;
      col = 1024 + ((u - 512) >> 5) * 64 + 2 * j;
    }
    const uint pr = *(const uint*)(qkv + (size_t)m * 1536 + col);
    const float tr = b2f((ushort)(pr & 0xffff));
    const float ti = b2f((ushort)(pr >> 16));
    const float c = fc[s * 32 + j], sn = fs[s * 32 + j];
    float orr = tr * c - ti * sn;
    float oi = tr * sn + ti * c;
    if (u < 512) {
      orr *= 0.18033688f;  // (1/sqrt(64)) * log2(e)
      oi *= 0.18033688f;
      const uint w = (uint)f2b(orr) | ((uint)f2b(oi) << 16);
      *(uint*)(qh + ((size_t)(b * 16 + (u >> 5)) * 2048 + s) * 64 + 2 * j) = w;
    } else {
      const uint w = (uint)f2b(orr) | ((uint)f2b(oi) << 16);
      const int kv = (u - 512) >> 5;
      *(uint*)(kh + ((size_t)(b * 4 + kv) * 2048 + s) * 64 + 2 * j) = w;
    }
    return;
  }
  // V transpose: 256 blocks
  const int id = blockIdx.x - 10240;
  const int st = id & 31, kv = (id >> 5) & 3, b = id >> 7;
  const int tid = threadIdx.x;
  for (int e = tid; e < 4096; e += 256) {
    const int r = e >> 6, c = e & 63;
    tile[r][c] =
        qkv[(size_t)(b * 2048 + st * 64 + r) * 1536 + 1280 + kv * 64 + c];
  }
  __syncthreads();
  for (int e = tid; e < 4096; e += 256) {
    const int d = e >> 6, c = e & 63;
    vT[((size_t)(b * 4 + kv) * 64 + d) * 2048 + st * 64 + c] = tile[c][d];
  }
}

// ---------------- Flash attention v6: 1-wave blocks, barrier-free ---------
// 2048 blocks x 64 thr; block = (bh, t) one 32-row q-tile, t = gid>>5 so a
// CU's stride-256 block set spans t in {t0, t0+8, ..} (balanced ~1.10).
// Single-buffered LDS KV (16KB) with issue-early staging: ds_reads drain,
// next stage issues, compute covers L2 latency; vmcnt(0) at loop top.
// NO s_barrier anywhere. Fixed-max softmax (log2 domain, shift 12).
// S^T = mfma(K, Q): lane holds q = lane&31, 16 keys at crow(r,hi).
// O^T = mfma(V^T, P^T): lane holds q = lane&31, d = dt*32 + crow(r,hi).

#define MCONST 12.0f

__device__ __forceinline__ void astep2(const bf8 (&kfA)[4], const bf8 (&kfB)[4],
                                       const bf8 (&vfA)[4], const bf8 (&vfB)[4],
                                       const bf8 (&qf)[4], f32x16& o0,
                                       f32x16& o1, float& l, int k0, int qg,
                                       bool maskt, int hi) {
  f32x16 s0 = {}, s1 = {};
  __builtin_amdgcn_s_setprio(1);
#pragma unroll
  for (int ks = 0; ks < 4; ++ks) s0 = mfma32(kfA[ks], qf[ks], s0);
#pragma unroll
  for (int ks = 0; ks < 4; ++ks) s1 = mfma32(kfB[ks], qf[ks], s1);
  __builtin_amdgcn_s_setprio(0);
  if (maskt) {
#pragma unroll
    for (int r = 0; r < 16; ++r) {
      const int key = k0 + (r & 3) + 8 * (r >> 2) + 4 * hi;
      if (key > qg) s0[r] = -1e30f;
      if (key + 32 > qg) s1[r] = -1e30f;
    }
  }
  float t[16];
#pragma unroll
  for (int r = 0; r < 16; ++r) {
    s0[r] = fexp2(s0[r] - MCONST);
    s1[r] = fexp2(s1[r] - MCONST);
    t[r] = s0[r] + s1[r];
  }
#pragma unroll
  for (int st = 8; st > 0; st >>= 1)
#pragma unroll
    for (int r = 0; r < st; ++r) t[r] += t[r + st];
  l += t[0] + __shfl_xor(t[0], 32);
  bf8 pa[4];
  {
    uint a0 = cvtpk(s0[0], s0[1]), a1 = cvtpk(s0[2], s0[3]);
    uint b0 = cvtpk(s0[4], s0[5]), b1 = cvtpk(s0[6], s0[7]);
    plswap(a0, b0);
    plswap(a1, b1);
    i32x4 w = {(int)a0, (int)a1, (int)b0, (int)b1};
    pa[0] = __builtin_bit_cast(bf8, w);
    uint c0 = cvtpk(s0[8], s0[9]), c1 = cvtpk(s0[10], s0[11]);
    uint d0 = cvtpk(s0[12], s0[13]), d1 = cvtpk(s0[14], s0[15]);
    plswap(c0, d0);
    plswap(c1, d1);
    i32x4 w2 = {(int)c0, (int)c1, (int)d0, (int)d1};
    pa[1] = __builtin_bit_cast(bf8, w2);
  }
  {
    uint a0 = cvtpk(s1[0], s1[1]), a1 = cvtpk(s1[2], s1[3]);
    uint b0 = cvtpk(s1[4], s1[5]), b1 = cvtpk(s1[6], s1[7]);
    plswap(a0, b0);
    plswap(a1, b1);
    i32x4 w = {(int)a0, (int)a1, (int)b0, (int)b1};
    pa[2] = __builtin_bit_cast(bf8, w);
    uint c0 = cvtpk(s1[8], s1[9]), c1 = cvtpk(s1[10], s1[11]);
    uint d0 = cvtpk(s1[12], s1[13]), d1 = cvtpk(s1[14], s1[15]);
    plswap(c0, d0);
    plswap(c1, d1);
    i32x4 w2 = {(int)c0, (int)c1, (int)d0, (int)d1};
    pa[3] = __builtin_bit_cast(bf8, w2);
  }
  __builtin_amdgcn_s_setprio(1);
#pragma unroll
  for (int ks = 0; ks < 4; ++ks) o0 = mfma32(vfA[ks], pa[ks], o0);
#pragma unroll
  for (int ks = 0; ks < 4; ++ks) o1 = mfma32(vfB[ks], pa[ks], o1);
  __builtin_amdgcn_s_setprio(0);
}

__device__ __forceinline__ void tile_out(ushort* ow, const f32x16& o0,
                                         const f32x16& o1, float l, int b,
                                         int h, int qw, int l31, int hi,
                                         int lane, ushort* ao) {
  const float inv = 1.0f / l;
#pragma unroll
  for (int dt = 0; dt < 2; ++dt)
#pragma unroll
    for (int rq = 0; rq < 4; ++rq) {
      const f32x16& ac = dt ? o1 : o0;
      uint2 w;
      w.x = (uint)f2b(ac[rq * 4 + 0] * inv) |
            ((uint)f2b(ac[rq * 4 + 1] * inv) << 16);
      w.y = (uint)f2b(ac[rq * 4 + 2] * inv) |
            ((uint)f2b(ac[rq * 4 + 3] * inv) << 16);
      const int d = dt * 32 + 8 * rq + 4 * hi;
      *(uint2*)&ow[l31 * 66 + d] = w;
    }
  asm volatile("s_waitcnt lgkmcnt(0)" ::: "memory");
  __builtin_amdgcn_sched_barrier(0);
  const int rrow = lane >> 4;
  const int rcol = (lane & 15) * 4;
  const size_t gbase = ((size_t)b * 2048 + qw) * 1024 + h * 64;
#pragma unroll
  for (int i = 0; i < 8; ++i) {
    const int rw = i * 4 + rrow;
    uint2 v = *(const uint2*)&ow[rw * 66 + rcol];
    *(uint2*)&ao[gbase + (size_t)rw * 1024 + rcol] = v;
  }
}

__global__ __launch_bounds__(64) void attn_fwd(const ushort* __restrict__ qh,
                                               const ushort* __restrict__ kh,
                                               const ushort* __restrict__ vT,
                                               ushort* __restrict__ ao) {
  __shared__ ushort kls[4096];  // 8KB K tile (64x64 bf16, swizzled)
  __shared__ ushort vls[4096];  // 8KB V tile (64d x 64k, swizzled)
  const int lane = threadIdx.x;
  const int l31 = lane & 31, hi = lane >> 5;
  const int gid = blockIdx.x;  // 2048
  const int bh = gid & 31;
  const int t = gid >> 5;  // 0..63, 32-row q tile
  const int b = bh >> 4, h = bh & 15;
  const int kv = h >> 2;
  const int n = (32 * t + 95) >> 6;  // KV tiles needed: 1..32
  const int qg = t * 32 + l31;

  const ushort* kbase = kh + (size_t)(b * 4 + kv) * 2048 * 64;
  const ushort* vbase = vT + (size_t)(b * 4 + kv) * 64 * 2048;

  auto stage = [&](int k0) {
#pragma unroll
    for (int jj = 0; jj < 8; ++jj) {
      const int i = jj * 64 + lane;
      const int r = i >> 3, s = i & 7;
      const int sw = (s ^ (r & 7)) << 3;
      gload16(kbase + (size_t)(k0 + r) * 64 + sw, kls + jj * 512);
      gload16(vbase + (size_t)r * 2048 + k0 + sw, vls + jj * 512);
    }
  };

  stage(0);

  bf8 qf[4];
  {
    const ushort* qb = qh + ((size_t)bh * 2048 + qg) * 64 + hi * 8;
#pragma unroll
    for (int ks = 0; ks < 4; ++ks) qf[ks] = *(const bf8*)(qb + ks * 16);
  }

  f32x16 o0 = {}, o1 = {};
  float l = 0.f;
  const int sw0 = l31 & 7;

  for (int it = 0; it < n; ++it) {
    asm volatile("s_waitcnt vmcnt(0)" ::: "memory");
    bf8 kfA[4], kfB[4], vfA[4], vfB[4];
#pragma unroll
    for (int ks = 0; ks < 4; ++ks) {
      const int c2 = 2 * ks + hi;
      const int off = (c2 ^ sw0) << 3;
      kfA[ks] = *(const bf8*)&kls[l31 * 64 + off];
      kfB[ks] = *(const bf8*)&kls[(32 + l31) * 64 + off];
      vfA[ks] = *(const bf8*)&vls[l31 * 64 + off];
      vfB[ks] = *(const bf8*)&vls[(32 + l31) * 64 + off];
    }
    asm volatile("s_waitcnt lgkmcnt(0)" ::: "memory");
    __builtin_amdgcn_sched_barrier(0);
    if (it + 1 < n) stage((it + 1) * 64);  // overwrite is safe: reads drained
    astep2(kfA, kfB, vfA, vfB, qf, o0, o1, l, it * 64, qg, it == n - 1, hi);
  }
  // epilogue reuses K buffer as transpose scratch (staging finished)
  tile_out(kls, o0, o1, l, b, h, t * 32, l31, hi, lane, ao);
}

extern "C" void kernel_launch(void* const* d_in, const int* in_sizes, int n_in,
                              void* d_out, int out_size, void* d_ws,
                              size_t ws_size, hipStream_t stream) {
  (void)in_sizes; (void)n_in; (void)out_size; (void)ws_size;
  const float* x = (const float*)d_in[0];
  const float* wq = (const float*)d_in[1];
  const float* wk = (const float*)d_in[2];
  const float* wv = (const float*)d_in[3];
  const float* wo = (const float*)d_in[4];
  const float* fc = (const float*)d_in[5];
  const float* fs = (const float*)d_in[6];
  float* out = (float*)d_out;

  ushort* xb = (ushort*)d_ws;               // 4096x1024
  ushort* wqkvT = xb + 4194304;             // 1536x1024
  ushort* woT = wqkvT + 1572864;            // 1024x1024
  ushort* qkv = woT + 1048576;              // 4096x1536
  ushort* qh = qkv + 6291456;               // 32x2048x64
  ushort* kh = qh + 4194304;                // 8x2048x64
  ushort* vTb = kh + 1048576;               // 8x64x2048
  ushort* ao = vTb + 1048576;               // 4096x1024

  prep1<<<6656, 256, 0, stream>>>(x, wq, wk, wv, wo, xb, wqkvT, woT);
  gemm_bt<true><<<dim3(12, 64), 256, 0, stream>>>(xb, wqkvT, qkv, 4096, 1536, 1024);
  prep2<<<10496, 256, 0, stream>>>(qkv, fc, fs, qh, kh, vTb);
  attn_fwd<<<2048, 64, 0, stream>>>(qh, kh, vTb, ao);
  gemm_bt<false><<<dim3(8, 64), 256, 0, stream>>>(ao, woT, out, 4096, 1024, 1024);
}

// Round 14
// 115.950 us; speedup vs baseline: 1.0908x; 1.0082x over previous
//
#include <hip/hip_runtime.h>

typedef short bf8 __attribute__((ext_vector_type(8)));   // 8 bf16 in 4 VGPRs
typedef float f32x4 __attribute__((ext_vector_type(4)));
typedef float f32x16 __attribute__((ext_vector_type(16)));
typedef int i32x4 __attribute__((ext_vector_type(4)));

__device__ __forceinline__ ushort f2b(float f) {
  unsigned x = __builtin_bit_cast(unsigned, f);
  unsigned r = (x + 0x7fffu + ((x >> 16) & 1u)) >> 16;
  return (ushort)r;
}
__device__ __forceinline__ float b2f(ushort u) {
  unsigned x = ((unsigned)u) << 16;
  return __builtin_bit_cast(float, x);
}

__device__ __forceinline__ f32x4 mfma16(bf8 a, bf8 b, f32x4 c) {
  return __builtin_amdgcn_mfma_f32_16x16x32_bf16(a, b, c, 0, 0, 0);
}
__device__ __forceinline__ f32x16 mfma32(bf8 a, bf8 b, f32x16 c) {
  return __builtin_amdgcn_mfma_f32_32x32x16_bf16(a, b, c, 0, 0, 0);
}

__device__ __forceinline__ float fexp2(float x) {
#if __has_builtin(__builtin_amdgcn_exp2f)
  return __builtin_amdgcn_exp2f(x);
#else
  return exp2f(x);
#endif
}

__device__ __forceinline__ uint cvtpk(float lo, float hi_) {
  uint r;
  asm("v_cvt_pk_bf16_f32 %0, %1, %2" : "=v"(r) : "v"(lo), "v"(hi_));
  return r;
}
__device__ __forceinline__ void plswap(uint& a, uint& b) {
  asm("v_permlane32_swap_b32 %0, %1" : "+v"(a), "+v"(b));
}

__device__ __forceinline__ void gload16(const ushort* g, ushort* l) {
  __builtin_amdgcn_global_load_lds(
      (const __attribute__((address_space(1))) void*)g,
      (__attribute__((address_space(3))) void*)l, 16, 0, 0);
}

// ---------------- prep1: cast x (f32->bf16) + all weight transposes ------
__global__ __launch_bounds__(256) void prep1(
    const float* __restrict__ x, const float* __restrict__ wq,
    const float* __restrict__ wk, const float* __restrict__ wv,
    const float* __restrict__ wo, ushort* __restrict__ xb,
    ushort* __restrict__ wqkvT, ushort* __restrict__ woT) {
  __shared__ float tile[32][33];
  const int bid = blockIdx.x;
  if (bid < 4096) {
    const int i = (bid * 256 + threadIdx.x) * 4;
    float4 v = *(const float4*)(x + i);
    ushort4 o;
    o.x = f2b(v.x); o.y = f2b(v.y); o.z = f2b(v.z); o.w = f2b(v.w);
    *(ushort4*)(xb + i) = o;
    return;
  }
  int t = bid - 4096;  // 0..2559
  const float* src;
  ushort* dst;
  int N;
  if (t < 1024) {
    src = wq; dst = wqkvT; N = 1024;
  } else if (t < 1280) {
    src = wk; dst = wqkvT + 1024 * 1024; N = 256; t -= 1024;
  } else if (t < 1536) {
    src = wv; dst = wqkvT + 1280 * 1024; N = 256; t -= 1280;
  } else {
    src = wo; dst = woT; N = 1024; t -= 1536;
  }
  const int kx = (t & 31) * 32, nx = (t >> 5) * 32;
  const int tx = threadIdx.x & 31, ty = threadIdx.x >> 5;
#pragma unroll
  for (int i = ty; i < 32; i += 8)
    tile[i][tx] = src[(size_t)(kx + i) * N + nx + tx];
  __syncthreads();
#pragma unroll
  for (int i = ty; i < 32; i += 8)
    dst[(size_t)(nx + i) * 1024 + kx + tx] = f2b(tile[tx][i]);
}

// ------- GEMM C[M][N] = A[M][K]*Bt[N][K]^T; 64x128 tile, BK=64, 4 waves --
// 768/512 blocks -> exactly 3/2 blocks per CU; 16 MFMAs between drains.
template <bool OUT_BF16>
__global__ __launch_bounds__(256) void gemm_bt(const ushort* __restrict__ A,
                                               const ushort* __restrict__ Bt,
                                               void* __restrict__ Cv, int M,
                                               int N, int K) {
  __shared__ ushort aL[64 * 64];    // 8 KB
  __shared__ ushort bL[128 * 64];   // 16 KB
  const int tid = threadIdx.x;
  const int wid = tid >> 6, lane = tid & 63;
  const int l15 = lane & 15, l4 = lane >> 4;
  const int bm = blockIdx.y * 64, bn = blockIdx.x * 128;
  const int wr = (wid & 1) * 32, wc = (wid >> 1) * 64;
  f32x4 acc[2][4] = {};
  for (int kb = 0; kb < K; kb += 64) {
    __syncthreads();
#pragma unroll
    for (int i = 0; i < 2; ++i) {  // A: 64x64 = 512 chunks, 2/thread
      const int e = (i * 256 + tid) * 8;
      const int r = e >> 6, c = e & 63;
      gload16(A + (size_t)(bm + r) * K + kb + c, &aL[i * 2048 + wid * 512]);
    }
#pragma unroll
    for (int i = 0; i < 4; ++i) {  // B: 128x64 = 1024 chunks, 4/thread
      const int e = (i * 256 + tid) * 8;
      const int r = e >> 6, c = e & 63;
      gload16(Bt + (size_t)(bn + r) * K + kb + c, &bL[i * 2048 + wid * 512]);
    }
    asm volatile("s_waitcnt vmcnt(0)" ::: "memory");
    __syncthreads();
    bf8 af[2][2], bfr[4][2];
#pragma unroll
    for (int i = 0; i < 2; ++i)
#pragma unroll
      for (int kk = 0; kk < 2; ++kk)
        af[i][kk] =
            *(const bf8*)&aL[(wr + i * 16 + l15) * 64 + kk * 32 + l4 * 8];
#pragma unroll
    for (int j = 0; j < 4; ++j)
#pragma unroll
      for (int kk = 0; kk < 2; ++kk)
        bfr[j][kk] =
            *(const bf8*)&bL[(wc + j * 16 + l15) * 64 + kk * 32 + l4 * 8];
#pragma unroll
    for (int kk = 0; kk < 2; ++kk)
#pragma unroll
      for (int i = 0; i < 2; ++i)
#pragma unroll
        for (int j = 0; j < 4; ++j)
          acc[i][j] = mfma16(af[i][kk], bfr[j][kk], acc[i][j]);
  }
#pragma unroll
  for (int i = 0; i < 2; ++i)
#pragma unroll
    for (int j = 0; j < 4; ++j)
#pragma unroll
      for (int r = 0; r < 4; ++r) {
        const size_t row = bm + wr + i * 16 + l4 * 4 + r;
        const size_t col = bn + wc + j * 16 + l15;
        if constexpr (OUT_BF16)
          ((ushort*)Cv)[row * N + col] = f2b(acc[i][j][r]);
        else
          ((float*)Cv)[row * N + col] = acc[i][j][r];
      }
}

// ---------------- prep2: RoPE for Q,K + V transpose ----------------
// Q is pre-scaled by 0.125*log2(e) so attention scores are in log2 domain.
__global__ __launch_bounds__(256) void prep2(const ushort* __restrict__ qkv,
                                             const float* __restrict__ fc,
                                             const float* __restrict__ fs,
                                             ushort* __restrict__ qh,
                                             ushort* __restrict__ kh,
                                             ushort* __restrict__ vT) {
  __shared__ ushort tile[64][65];
  if (blockIdx.x < 10240) {
    const int idx = blockIdx.x * 256 + threadIdx.x;  // 4096*640 total
    const int u = idx % 640;
    const int m = idx / 640;
    const int s = m & 2047, b = m >> 11;
    int col, j;
    if (u < 512) {
      j = u & 31;
      col = (u >> 5) * 64 + 2 * j;
    } else {
      j = (u - 512) & 31;
      col = 1024 + ((u - 512) >> 5) * 64 + 2 * j;
    }
    const uint pr = *(const uint*)(qkv + (size_t)m * 1536 + col);
    const float tr = b2f((ushort)(pr & 0xffff));
    const float ti = b2f((ushort)(pr >> 16));
    const float c = fc[s * 32 + j], sn = fs[s * 32 + j];
    float orr = tr * c - ti * sn;
    float oi = tr * sn + ti * c;
    if (u < 512) {
      orr *= 0.18033688f;  // (1/sqrt(64)) * log2(e)
      oi *= 0.18033688f;
      const uint w = (uint)f2b(orr) | ((uint)f2b(oi) << 16);
      *(uint*)(qh + ((size_t)(b * 16 + (u >> 5)) * 2048 + s) * 64 + 2 * j) = w;
    } else {
      const uint w = (uint)f2b(orr) | ((uint)f2b(oi) << 16);
      const int kv = (u - 512) >> 5;
      *(uint*)(kh + ((size_t)(b * 4 + kv) * 2048 + s) * 64 + 2 * j) = w;
    }
    return;
  }
  // V transpose: 256 blocks
  const int id = blockIdx.x - 10240;
  const int st = id & 31, kv = (id >> 5) & 3, b = id >> 7;
  const int tid = threadIdx.x;
  for (int e = tid; e < 4096; e += 256) {
    const int r = e >> 6, c = e & 63;
    tile[r][c] =
        qkv[(size_t)(b * 2048 + st * 64 + r) * 1536 + 1280 + kv * 64 + c];
  }
  __syncthreads();
  for (int e = tid; e < 4096; e += 256) {
    const int d = e >> 6, c = e & 63;
    vT[((size_t)(b * 4 + kv) * 64 + d) * 2048 + st * 64 + c] = tile[c][d];
  }
}

// ---------------- Flash attention v6: 1-wave blocks, barrier-free ---------
// 2048 blocks x 64 thr; block = (bh, t) one 32-row q-tile, t = gid>>5 so a
// CU's stride-256 block set spans t in {t0, t0+8, ..} (balanced ~1.10).
// Single-buffered LDS KV (16KB) with issue-early staging: ds_reads drain,
// next stage issues, compute covers L2 latency; vmcnt(0) at loop top.
// NO s_barrier anywhere. Fixed-max softmax (log2 domain, shift 12).
// S^T = mfma(K, Q): lane holds q = lane&31, 16 keys at crow(r,hi).
// O^T = mfma(V^T, P^T): lane holds q = lane&31, d = dt*32 + crow(r,hi).

#define MCONST 12.0f

__device__ __forceinline__ void astep2(const bf8 (&kfA)[4], const bf8 (&kfB)[4],
                                       const bf8 (&vfA)[4], const bf8 (&vfB)[4],
                                       const bf8 (&qf)[4], f32x16& o0,
                                       f32x16& o1, float& l, int k0, int qg,
                                       bool maskt, int hi) {
  f32x16 s0 = {}, s1 = {};
  __builtin_amdgcn_s_setprio(1);
#pragma unroll
  for (int ks = 0; ks < 4; ++ks) s0 = mfma32(kfA[ks], qf[ks], s0);
#pragma unroll
  for (int ks = 0; ks < 4; ++ks) s1 = mfma32(kfB[ks], qf[ks], s1);
  __builtin_amdgcn_s_setprio(0);
  if (maskt) {
#pragma unroll
    for (int r = 0; r < 16; ++r) {
      const int key = k0 + (r & 3) + 8 * (r >> 2) + 4 * hi;
      if (key > qg) s0[r] = -1e30f;
      if (key + 32 > qg) s1[r] = -1e30f;
    }
  }
  float t[16];
#pragma unroll
  for (int r = 0; r < 16; ++r) {
    s0[r] = fexp2(s0[r] - MCONST);
    s1[r] = fexp2(s1[r] - MCONST);
    t[r] = s0[r] + s1[r];
  }
#pragma unroll
  for (int st = 8; st > 0; st >>= 1)
#pragma unroll
    for (int r = 0; r < st; ++r) t[r] += t[r + st];
  l += t[0] + __shfl_xor(t[0], 32);
  bf8 pa[4];
  {
    uint a0 = cvtpk(s0[0], s0[1]), a1 = cvtpk(s0[2], s0[3]);
    uint b0 = cvtpk(s0[4], s0[5]), b1 = cvtpk(s0[6], s0[7]);
    plswap(a0, b0);
    plswap(a1, b1);
    i32x4 w = {(int)a0, (int)a1, (int)b0, (int)b1};
    pa[0] = __builtin_bit_cast(bf8, w);
    uint c0 = cvtpk(s0[8], s0[9]), c1 = cvtpk(s0[10], s0[11]);
    uint d0 = cvtpk(s0[12], s0[13]), d1 = cvtpk(s0[14], s0[15]);
    plswap(c0, d0);
    plswap(c1, d1);
    i32x4 w2 = {(int)c0, (int)c1, (int)d0, (int)d1};
    pa[1] = __builtin_bit_cast(bf8, w2);
  }
  {
    uint a0 = cvtpk(s1[0], s1[1]), a1 = cvtpk(s1[2], s1[3]);
    uint b0 = cvtpk(s1[4], s1[5]), b1 = cvtpk(s1[6], s1[7]);
    plswap(a0, b0);
    plswap(a1, b1);
    i32x4 w = {(int)a0, (int)a1, (int)b0, (int)b1};
    pa[2] = __builtin_bit_cast(bf8, w);
    uint c0 = cvtpk(s1[8], s1[9]), c1 = cvtpk(s1[10], s1[11]);
    uint d0 = cvtpk(s1[12], s1[13]), d1 = cvtpk(s1[14], s1[15]);
    plswap(c0, d0);
    plswap(c1, d1);
    i32x4 w2 = {(int)c0, (int)c1, (int)d0, (int)d1};
    pa[3] = __builtin_bit_cast(bf8, w2);
  }
  __builtin_amdgcn_s_setprio(1);
#pragma unroll
  for (int ks = 0; ks < 4; ++ks) o0 = mfma32(vfA[ks], pa[ks], o0);
#pragma unroll
  for (int ks = 0; ks < 4; ++ks) o1 = mfma32(vfB[ks], pa[ks], o1);
  __builtin_amdgcn_s_setprio(0);
}

__device__ __forceinline__ void tile_out(ushort* ow, const f32x16& o0,
                                         const f32x16& o1, float l, int b,
                                         int h, int qw, int l31, int hi,
                                         int lane, ushort* ao) {
  const float inv = 1.0f / l;
#pragma unroll
  for (int dt = 0; dt < 2; ++dt)
#pragma unroll
    for (int rq = 0; rq < 4; ++rq) {
      const f32x16& ac = dt ? o1 : o0;
      uint2 w;
      w.x = (uint)f2b(ac[rq * 4 + 0] * inv) |
            ((uint)f2b(ac[rq * 4 + 1] * inv) << 16);
      w.y = (uint)f2b(ac[rq * 4 + 2] * inv) |
            ((uint)f2b(ac[rq * 4 + 3] * inv) << 16);
      const int d = dt * 32 + 8 * rq + 4 * hi;
      *(uint2*)&ow[l31 * 66 + d] = w;
    }
  asm volatile("s_waitcnt lgkmcnt(0)" ::: "memory");
  __builtin_amdgcn_sched_barrier(0);
  const int rrow = lane >> 4;
  const int rcol = (lane & 15) * 4;
  const size_t gbase = ((size_t)b * 2048 + qw) * 1024 + h * 64;
#pragma unroll
  for (int i = 0; i < 8; ++i) {
    const int rw = i * 4 + rrow;
    uint2 v = *(const uint2*)&ow[rw * 66 + rcol];
    *(uint2*)&ao[gbase + (size_t)rw * 1024 + rcol] = v;
  }
}

__global__ __launch_bounds__(64) void attn_fwd(const ushort* __restrict__ qh,
                                               const ushort* __restrict__ kh,
                                               const ushort* __restrict__ vT,
                                               ushort* __restrict__ ao) {
  __shared__ ushort kls[4096];  // 8KB K tile (64x64 bf16, swizzled)
  __shared__ ushort vls[4096];  // 8KB V tile (64d x 64k, swizzled)
  const int lane = threadIdx.x;
  const int l31 = lane & 31, hi = lane >> 5;
  const int gid = blockIdx.x;  // 2048
  const int bh = gid & 31;
  const int t = gid >> 5;  // 0..63, 32-row q tile
  const int b = bh >> 4, h = bh & 15;
  const int kv = h >> 2;
  const int n = (32 * t + 95) >> 6;  // KV tiles needed: 1..32
  const int qg = t * 32 + l31;

  const ushort* kbase = kh + (size_t)(b * 4 + kv) * 2048 * 64;
  const ushort* vbase = vT + (size_t)(b * 4 + kv) * 64 * 2048;

  auto stage = [&](int k0) {
#pragma unroll
    for (int jj = 0; jj < 8; ++jj) {
      const int i = jj * 64 + lane;
      const int r = i >> 3, s = i & 7;
      const int sw = (s ^ (r & 7)) << 3;
      gload16(kbase + (size_t)(k0 + r) * 64 + sw, kls + jj * 512);
      gload16(vbase + (size_t)r * 2048 + k0 + sw, vls + jj * 512);
    }
  };

  stage(0);

  bf8 qf[4];
  {
    const ushort* qb = qh + ((size_t)bh * 2048 + qg) * 64 + hi * 8;
#pragma unroll
    for (int ks = 0; ks < 4; ++ks) qf[ks] = *(const bf8*)(qb + ks * 16);
  }

  f32x16 o0 = {}, o1 = {};
  float l = 0.f;
  const int sw0 = l31 & 7;

  for (int it = 0; it < n; ++it) {
    asm volatile("s_waitcnt vmcnt(0)" ::: "memory");
    bf8 kfA[4], kfB[4], vfA[4], vfB[4];
#pragma unroll
    for (int ks = 0; ks < 4; ++ks) {
      const int c2 = 2 * ks + hi;
      const int off = (c2 ^ sw0) << 3;
      kfA[ks] = *(const bf8*)&kls[l31 * 64 + off];
      kfB[ks] = *(const bf8*)&kls[(32 + l31) * 64 + off];
      vfA[ks] = *(const bf8*)&vls[l31 * 64 + off];
      vfB[ks] = *(const bf8*)&vls[(32 + l31) * 64 + off];
    }
    asm volatile("s_waitcnt lgkmcnt(0)" ::: "memory");
    __builtin_amdgcn_sched_barrier(0);
    if (it + 1 < n) stage((it + 1) * 64);  // overwrite is safe: reads drained
    astep2(kfA, kfB, vfA, vfB, qf, o0, o1, l, it * 64, qg, it == n - 1, hi);
  }
  // epilogue reuses K buffer as transpose scratch (staging finished)
  tile_out(kls, o0, o1, l, b, h, t * 32, l31, hi, lane, ao);
}

extern "C" void kernel_launch(void* const* d_in, const int* in_sizes, int n_in,
                              void* d_out, int out_size, void* d_ws,
                              size_t ws_size, hipStream_t stream) {
  (void)in_sizes; (void)n_in; (void)out_size; (void)ws_size;
  const float* x = (const float*)d_in[0];
  const float* wq = (const float*)d_in[1];
  const float* wk = (const float*)d_in[2];
  const float* wv = (const float*)d_in[3];
  const float* wo = (const float*)d_in[4];
  const float* fc = (const float*)d_in[5];
  const float* fs = (const float*)d_in[6];
  float* out = (float*)d_out;

  ushort* xb = (ushort*)d_ws;               // 4096x1024
  ushort* wqkvT = xb + 4194304;             // 1536x1024
  ushort* woT = wqkvT + 1572864;            // 1024x1024
  ushort* qkv = woT + 1048576;              // 4096x1536
  ushort* qh = qkv + 6291456;               // 32x2048x64
  ushort* kh = qh + 4194304;                // 8x2048x64
  ushort* vTb = kh + 1048576;               // 8x64x2048
  ushort* ao = vTb + 1048576;               // 4096x1024

  prep1<<<6656, 256, 0, stream>>>(x, wq, wk, wv, wo, xb, wqkvT, woT);
  gemm_bt<true><<<dim3(12, 64), 256, 0, stream>>>(xb, wqkvT, qkv, 4096, 1536, 1024);
  prep2<<<10496, 256, 0, stream>>>(qkv, fc, fs, qh, kh, vTb);
  attn_fwd<<<2048, 64, 0, stream>>>(qh, kh, vTb, ao);
  gemm_bt<false><<<dim3(8, 64), 256, 0, stream>>>(ao, woT, out, 4096, 1024, 1024);
}

// Round 15
// 112.897 us; speedup vs baseline: 1.1203x; 1.0270x over previous
//
#include <hip/hip_runtime.h>

typedef short bf8 __attribute__((ext_vector_type(8)));   // 8 bf16 in 4 VGPRs
typedef float f32x4 __attribute__((ext_vector_type(4)));
typedef float f32x16 __attribute__((ext_vector_type(16)));
typedef int i32x4 __attribute__((ext_vector_type(4)));

__device__ __forceinline__ ushort f2b(float f) {
  unsigned x = __builtin_bit_cast(unsigned, f);
  unsigned r = (x + 0x7fffu + ((x >> 16) & 1u)) >> 16;
  return (ushort)r;
}
__device__ __forceinline__ float b2f(ushort u) {
  unsigned x = ((unsigned)u) << 16;
  return __builtin_bit_cast(float, x);
}

__device__ __forceinline__ f32x4 mfma16(bf8 a, bf8 b, f32x4 c) {
  return __builtin_amdgcn_mfma_f32_16x16x32_bf16(a, b, c, 0, 0, 0);
}
__device__ __forceinline__ f32x16 mfma32(bf8 a, bf8 b, f32x16 c) {
  return __builtin_amdgcn_mfma_f32_32x32x16_bf16(a, b, c, 0, 0, 0);
}

__device__ __forceinline__ float fexp2(float x) {
#if __has_builtin(__builtin_amdgcn_exp2f)
  return __builtin_amdgcn_exp2f(x);
#else
  return exp2f(x);
#endif
}

__device__ __forceinline__ uint cvtpk(float lo, float hi_) {
  uint r;
  asm("v_cvt_pk_bf16_f32 %0, %1, %2" : "=v"(r) : "v"(lo), "v"(hi_));
  return r;
}
__device__ __forceinline__ void plswap(uint& a, uint& b) {
  asm("v_permlane32_swap_b32 %0, %1" : "+v"(a), "+v"(b));
}

__device__ __forceinline__ void gload16(const ushort* g, ushort* l) {
  __builtin_amdgcn_global_load_lds(
      (const __attribute__((address_space(1))) void*)g,
      (__attribute__((address_space(3))) void*)l, 16, 0, 0);
}

// ---------------- prep1: cast x (f32->bf16) + all weight transposes ------
__global__ __launch_bounds__(256) void prep1(
    const float* __restrict__ x, const float* __restrict__ wq,
    const float* __restrict__ wk, const float* __restrict__ wv,
    const float* __restrict__ wo, ushort* __restrict__ xb,
    ushort* __restrict__ wqkvT, ushort* __restrict__ woT) {
  __shared__ float tile[32][33];
  const int bid = blockIdx.x;
  if (bid < 4096) {
    const int i = (bid * 256 + threadIdx.x) * 4;
    float4 v = *(const float4*)(x + i);
    ushort4 o;
    o.x = f2b(v.x); o.y = f2b(v.y); o.z = f2b(v.z); o.w = f2b(v.w);
    *(ushort4*)(xb + i) = o;
    return;
  }
  int t = bid - 4096;  // 0..2559
  const float* src;
  ushort* dst;
  int N;
  if (t < 1024) {
    src = wq; dst = wqkvT; N = 1024;
  } else if (t < 1280) {
    src = wk; dst = wqkvT + 1024 * 1024; N = 256; t -= 1024;
  } else if (t < 1536) {
    src = wv; dst = wqkvT + 1280 * 1024; N = 256; t -= 1280;
  } else {
    src = wo; dst = woT; N = 1024; t -= 1536;
  }
  const int kx = (t & 31) * 32, nx = (t >> 5) * 32;
  const int tx = threadIdx.x & 31, ty = threadIdx.x >> 5;
#pragma unroll
  for (int i = ty; i < 32; i += 8)
    tile[i][tx] = src[(size_t)(kx + i) * N + nx + tx];
  __syncthreads();
#pragma unroll
  for (int i = ty; i < 32; i += 8)
    dst[(size_t)(nx + i) * 1024 + kx + tx] = f2b(tile[tx][i]);
}

// ------- GEMM C[M][N] = A[M][K]*Bt[N][K]^T; 64x128 tile, BK=64, 4 waves --
// 768/512 blocks -> exactly 3/2 blocks per CU; 16 MFMAs between drains.
template <bool OUT_BF16>
__global__ __launch_bounds__(256) void gemm_bt(const ushort* __restrict__ A,
                                               const ushort* __restrict__ Bt,
                                               void* __restrict__ Cv, int M,
                                               int N, int K) {
  __shared__ ushort aL[64 * 64];    // 8 KB
  __shared__ ushort bL[128 * 64];   // 16 KB
  const int tid = threadIdx.x;
  const int wid = tid >> 6, lane = tid & 63;
  const int l15 = lane & 15, l4 = lane >> 4;
  const int bm = blockIdx.y * 64, bn = blockIdx.x * 128;
  const int wr = (wid & 1) * 32, wc = (wid >> 1) * 64;
  f32x4 acc[2][4] = {};
  for (int kb = 0; kb < K; kb += 64) {
    __syncthreads();
#pragma unroll
    for (int i = 0; i < 2; ++i) {  // A: 64x64 = 512 chunks, 2/thread
      const int e = (i * 256 + tid) * 8;
      const int r = e >> 6, c = e & 63;
      gload16(A + (size_t)(bm + r) * K + kb + c, &aL[i * 2048 + wid * 512]);
    }
#pragma unroll
    for (int i = 0; i < 4; ++i) {  // B: 128x64 = 1024 chunks, 4/thread
      const int e = (i * 256 + tid) * 8;
      const int r = e >> 6, c = e & 63;
      gload16(Bt + (size_t)(bn + r) * K + kb + c, &bL[i * 2048 + wid * 512]);
    }
    asm volatile("s_waitcnt vmcnt(0)" ::: "memory");
    __syncthreads();
    bf8 af[2][2], bfr[4][2];
#pragma unroll
    for (int i = 0; i < 2; ++i)
#pragma unroll
      for (int kk = 0; kk < 2; ++kk)
        af[i][kk] =
            *(const bf8*)&aL[(wr + i * 16 + l15) * 64 + kk * 32 + l4 * 8];
#pragma unroll
    for (int j = 0; j < 4; ++j)
#pragma unroll
      for (int kk = 0; kk < 2; ++kk)
        bfr[j][kk] =
            *(const bf8*)&bL[(wc + j * 16 + l15) * 64 + kk * 32 + l4 * 8];
#pragma unroll
    for (int kk = 0; kk < 2; ++kk)
#pragma unroll
      for (int i = 0; i < 2; ++i)
#pragma unroll
        for (int j = 0; j < 4; ++j)
          acc[i][j] = mfma16(af[i][kk], bfr[j][kk], acc[i][j]);
  }
#pragma unroll
  for (int i = 0; i < 2; ++i)
#pragma unroll
    for (int j = 0; j < 4; ++j)
#pragma unroll
      for (int r = 0; r < 4; ++r) {
        const size_t row = bm + wr + i * 16 + l4 * 4 + r;
        const size_t col = bn + wc + j * 16 + l15;
        if constexpr (OUT_BF16)
          ((ushort*)Cv)[row * N + col] = f2b(acc[i][j][r]);
        else
          ((float*)Cv)[row * N + col] = acc[i][j][r];
      }
}

// ---------------- prep2: RoPE for Q,K + V transpose ----------------
// Q is pre-scaled by 0.125*log2(e) so attention scores are in log2 domain.
__global__ __launch_bounds__(256) void prep2(const ushort* __restrict__ qkv,
                                             const float* __restrict__ fc,
                                             const float* __restrict__ fs,
                                             ushort* __restrict__ qh,
                                             ushort* __restrict__ kh,
                                             ushort* __restrict__ vT) {
  __shared__ ushort tile[64][65];
  if (blockIdx.x < 10240) {
    const int idx = blockIdx.x * 256 + threadIdx.x;  // 4096*640 total
    const int u = idx % 640;
    const int m = idx / 640;
    const int s = m & 2047, b = m >> 11;
    int col, j;
    if (u < 512) {
      j = u & 31;
      col = (u >> 5) * 64 + 2 * j;
    } else {
      j = (u - 512) & 31;
      col = 1024 + ((u - 512) >> 5) * 64 + 2 * j;
    }
    const uint pr = *(const uint*)(qkv + (size_t)m * 1536 + col);
    const float tr = b2f((ushort)(pr & 0xffff));
    const float ti = b2f((ushort)(pr >> 16));
    const float c = fc[s * 32 + j], sn = fs[s * 32 + j];
    float orr = tr * c - ti * sn;
    float oi = tr * sn + ti * c;
    if (u < 512) {
      orr *= 0.18033688f;  // (1/sqrt(64)) * log2(e)
      oi *= 0.18033688f;
      const uint w = (uint)f2b(orr) | ((uint)f2b(oi) << 16);
      *(uint*)(qh + ((size_t)(b * 16 + (u >> 5)) * 2048 + s) * 64 + 2 * j) = w;
    } else {
      const uint w = (uint)f2b(orr) | ((uint)f2b(oi) << 16);
      const int kv = (u - 512) >> 5;
      *(uint*)(kh + ((size_t)(b * 4 + kv) * 2048 + s) * 64 + 2 * j) = w;
    }
    return;
  }
  // V transpose: 256 blocks
  const int id = blockIdx.x - 10240;
  const int st = id & 31, kv = (id >> 5) & 3, b = id >> 7;
  const int tid = threadIdx.x;
  for (int e = tid; e < 4096; e += 256) {
    const int r = e >> 6, c = e & 63;
    tile[r][c] =
        qkv[(size_t)(b * 2048 + st * 64 + r) * 1536 + 1280 + kv * 64 + c];
  }
  __syncthreads();
  for (int e = tid; e < 4096; e += 256) {
    const int d = e >> 6, c = e & 63;
    vT[((size_t)(b * 4 + kv) * 64 + d) * 2048 + st * 64 + c] = tile[c][d];
  }
}

// ---------------- Flash attention v9: 4 heads share one staged KV --------
// 512 blocks x 256 thr (4 waves). Block = (b, kv, q-tile t); wave w computes
// head h = 4*kv + w; all 4 waves share ONE single-buffered 16KB K/V stage
// (GQA: the 4 heads of a kv group use identical K/V). Staging per wave drops
// 4x vs v6. Complement halves balance CUs exactly: gid and gid+256 share p,
// t = p (n=(p+2)/2) and t = 63-p, so every SIMD gets nA+nB = 33 step-slots.
// Per step: own-vmcnt(0) -> barrier (all loads landed) -> ds_read frags ->
// lgkm(0) -> barrier (safe overwrite) -> stage(next) -> astep (hides load).
// Fixed-max softmax (log2 domain, shift 12).

#define MCONST 12.0f

__device__ __forceinline__ void astep2(const bf8 (&kfA)[4], const bf8 (&kfB)[4],
                                       const bf8 (&vfA)[4], const bf8 (&vfB)[4],
                                       const bf8 (&qf)[4], f32x16& o0,
                                       f32x16& o1, float& l, int k0, int qg,
                                       bool maskt, int hi) {
  f32x16 s0 = {}, s1 = {};
  __builtin_amdgcn_s_setprio(1);
#pragma unroll
  for (int ks = 0; ks < 4; ++ks) s0 = mfma32(kfA[ks], qf[ks], s0);
#pragma unroll
  for (int ks = 0; ks < 4; ++ks) s1 = mfma32(kfB[ks], qf[ks], s1);
  __builtin_amdgcn_s_setprio(0);
  if (maskt) {
#pragma unroll
    for (int r = 0; r < 16; ++r) {
      const int key = k0 + (r & 3) + 8 * (r >> 2) + 4 * hi;
      if (key > qg) s0[r] = -1e30f;
      if (key + 32 > qg) s1[r] = -1e30f;
    }
  }
  float t[16];
#pragma unroll
  for (int r = 0; r < 16; ++r) {
    s0[r] = fexp2(s0[r] - MCONST);
    s1[r] = fexp2(s1[r] - MCONST);
    t[r] = s0[r] + s1[r];
  }
#pragma unroll
  for (int st = 8; st > 0; st >>= 1)
#pragma unroll
    for (int r = 0; r < st; ++r) t[r] += t[r + st];
  l += t[0] + __shfl_xor(t[0], 32);
  bf8 pa[4];
  {
    uint a0 = cvtpk(s0[0], s0[1]), a1 = cvtpk(s0[2], s0[3]);
    uint b0 = cvtpk(s0[4], s0[5]), b1 = cvtpk(s0[6], s0[7]);
    plswap(a0, b0);
    plswap(a1, b1);
    i32x4 w = {(int)a0, (int)a1, (int)b0, (int)b1};
    pa[0] = __builtin_bit_cast(bf8, w);
    uint c0 = cvtpk(s0[8], s0[9]), c1 = cvtpk(s0[10], s0[11]);
    uint d0 = cvtpk(s0[12], s0[13]), d1 = cvtpk(s0[14], s0[15]);
    plswap(c0, d0);
    plswap(c1, d1);
    i32x4 w2 = {(int)c0, (int)c1, (int)d0, (int)d1};
    pa[1] = __builtin_bit_cast(bf8, w2);
  }
  {
    uint a0 = cvtpk(s1[0], s1[1]), a1 = cvtpk(s1[2], s1[3]);
    uint b0 = cvtpk(s1[4], s1[5]), b1 = cvtpk(s1[6], s1[7]);
    plswap(a0, b0);
    plswap(a1, b1);
    i32x4 w = {(int)a0, (int)a1, (int)b0, (int)b1};
    pa[2] = __builtin_bit_cast(bf8, w);
    uint c0 = cvtpk(s1[8], s1[9]), c1 = cvtpk(s1[10], s1[11]);
    uint d0 = cvtpk(s1[12], s1[13]), d1 = cvtpk(s1[14], s1[15]);
    plswap(c0, d0);
    plswap(c1, d1);
    i32x4 w2 = {(int)c0, (int)c1, (int)d0, (int)d1};
    pa[3] = __builtin_bit_cast(bf8, w2);
  }
  __builtin_amdgcn_s_setprio(1);
#pragma unroll
  for (int ks = 0; ks < 4; ++ks) o0 = mfma32(vfA[ks], pa[ks], o0);
#pragma unroll
  for (int ks = 0; ks < 4; ++ks) o1 = mfma32(vfB[ks], pa[ks], o1);
  __builtin_amdgcn_s_setprio(0);
}

__device__ __forceinline__ void tile_out(ushort* ow, const f32x16& o0,
                                         const f32x16& o1, float l, int b,
                                         int h, int qw, int l31, int hi,
                                         int lane, ushort* ao) {
  const float inv = 1.0f / l;
#pragma unroll
  for (int dt = 0; dt < 2; ++dt)
#pragma unroll
    for (int rq = 0; rq < 4; ++rq) {
      const f32x16& ac = dt ? o1 : o0;
      uint2 w;
      w.x = (uint)f2b(ac[rq * 4 + 0] * inv) |
            ((uint)f2b(ac[rq * 4 + 1] * inv) << 16);
      w.y = (uint)f2b(ac[rq * 4 + 2] * inv) |
            ((uint)f2b(ac[rq * 4 + 3] * inv) << 16);
      const int d = dt * 32 + 8 * rq + 4 * hi;
      *(uint2*)&ow[l31 * 66 + d] = w;
    }
  asm volatile("s_waitcnt lgkmcnt(0)" ::: "memory");
  __builtin_amdgcn_sched_barrier(0);
  const int rrow = lane >> 4;
  const int rcol = (lane & 15) * 4;
  const size_t gbase = ((size_t)b * 2048 + qw) * 1024 + h * 64;
#pragma unroll
  for (int i = 0; i < 8; ++i) {
    const int rw = i * 4 + rrow;
    uint2 v = *(const uint2*)&ow[rw * 66 + rcol];
    *(uint2*)&ao[gbase + (size_t)rw * 1024 + rcol] = v;
  }
}

__global__ __launch_bounds__(256) void attn_fwd(const ushort* __restrict__ qh,
                                                const ushort* __restrict__ kh,
                                                const ushort* __restrict__ vT,
                                                ushort* __restrict__ ao) {
  __shared__ ushort kls[4096];      // 8KB K tile (64x64 bf16, swizzled)
  __shared__ ushort vls[4096];      // 8KB V tile (64d x 64k, swizzled)
  __shared__ ushort olds[4][2176];  // per-wave epilogue transpose scratch
  const int tid = threadIdx.x;
  const int wid = tid >> 6, lane = tid & 63;
  const int l31 = lane & 31, hi = lane >> 5;
  const int gid = blockIdx.x;  // 512
  const int bk = gid & 7;      // b*4 + kv
  const int b = bk >> 2, kv = bk & 3;
  const int rest = gid >> 3;   // 0..63
  const int p = rest & 31, half = rest >> 5;
  const int t = half ? (63 - p) : p;  // CU c gets gid c (half0) + c+256 (half1)
  const int h = kv * 4 + wid;
  const int n = (32 * t + 95) >> 6;  // KV tiles: half0 1..16, half1 17..32
  const int qg = t * 32 + l31;

  const ushort* kbase = kh + (size_t)(b * 4 + kv) * 2048 * 64;
  const ushort* vbase = vT + (size_t)(b * 4 + kv) * 64 * 2048;

  // wave w stages chunks {w, w+4} of both K and V (4 gloads/wave/step)
  auto stage = [&](int k0) {
#pragma unroll
    for (int jj2 = 0; jj2 < 2; ++jj2) {
      const int jj = wid + jj2 * 4;
      const int i = jj * 64 + lane;
      const int r = i >> 3, s = i & 7;
      const int sw = (s ^ (r & 7)) << 3;
      gload16(kbase + (size_t)(k0 + r) * 64 + sw, kls + jj * 512);
      gload16(vbase + (size_t)r * 2048 + k0 + sw, vls + jj * 512);
    }
  };

  stage(0);

  bf8 qf[4];
  {
    const ushort* qb = qh + ((size_t)(b * 16 + h) * 2048 + qg) * 64 + hi * 8;
#pragma unroll
    for (int ks = 0; ks < 4; ++ks) qf[ks] = *(const bf8*)(qb + ks * 16);
  }

  f32x16 o0 = {}, o1 = {};
  float l = 0.f;
  const int sw0 = l31 & 7;

  for (int it = 0; it < n; ++it) {
    asm volatile("s_waitcnt vmcnt(0)" ::: "memory");  // own loads done
    __builtin_amdgcn_s_barrier();                     // everyone's loads done
    asm volatile("" ::: "memory");
    bf8 kfA[4], kfB[4], vfA[4], vfB[4];
#pragma unroll
    for (int ks = 0; ks < 4; ++ks) {
      const int c2 = 2 * ks + hi;
      const int off = (c2 ^ sw0) << 3;
      kfA[ks] = *(const bf8*)&kls[l31 * 64 + off];
      kfB[ks] = *(const bf8*)&kls[(32 + l31) * 64 + off];
      vfA[ks] = *(const bf8*)&vls[l31 * 64 + off];
      vfB[ks] = *(const bf8*)&vls[(32 + l31) * 64 + off];
    }
    asm volatile("s_waitcnt lgkmcnt(0)" ::: "memory");
    __builtin_amdgcn_sched_barrier(0);
    __builtin_amdgcn_s_barrier();  // everyone's reads done -> safe overwrite
    if (it + 1 < n) stage((it + 1) * 64);
    astep2(kfA, kfB, vfA, vfB, qf, o0, o1, l, it * 64, qg, it == n - 1, hi);
  }
  tile_out(olds[wid], o0, o1, l, b, h, t * 32, l31, hi, lane, ao);
}

extern "C" void kernel_launch(void* const* d_in, const int* in_sizes, int n_in,
                              void* d_out, int out_size, void* d_ws,
                              size_t ws_size, hipStream_t stream) {
  (void)in_sizes; (void)n_in; (void)out_size; (void)ws_size;
  const float* x = (const float*)d_in[0];
  const float* wq = (const float*)d_in[1];
  const float* wk = (const float*)d_in[2];
  const float* wv = (const float*)d_in[3];
  const float* wo = (const float*)d_in[4];
  const float* fc = (const float*)d_in[5];
  const float* fs = (const float*)d_in[6];
  float* out = (float*)d_out;

  ushort* xb = (ushort*)d_ws;               // 4096x1024
  ushort* wqkvT = xb + 4194304;             // 1536x1024
  ushort* woT = wqkvT + 1572864;            // 1024x1024
  ushort* qkv = woT + 1048576;              // 4096x1536
  ushort* qh = qkv + 6291456;               // 32x2048x64
  ushort* kh = qh + 4194304;                // 8x2048x64
  ushort* vTb = kh + 1048576;               // 8x64x2048
  ushort* ao = vTb + 1048576;               // 4096x1024

  prep1<<<6656, 256, 0, stream>>>(x, wq, wk, wv, wo, xb, wqkvT, woT);
  gemm_bt<true><<<dim3(12, 64), 256, 0, stream>>>(xb, wqkvT, qkv, 4096, 1536, 1024);
  prep2<<<10496, 256, 0, stream>>>(qkv, fc, fs, qh, kh, vTb);
  attn_fwd<<<512, 256, 0, stream>>>(qh, kh, vTb, ao);
  gemm_bt<false><<<dim3(8, 64), 256, 0, stream>>>(ao, woT, out, 4096, 1024, 1024);
}